// Round 5
// baseline (467.225 us; speedup 1.0000x reference)
//
#include <hip/hip_runtime.h>
#include <hip/hip_bf16.h>
#include <stdint.h>

typedef __bf16 bf16_t;
typedef __bf16 bf16x4 __attribute__((ext_vector_type(4)));
typedef __bf16 bf16x8 __attribute__((ext_vector_type(8)));
typedef float f32x4 __attribute__((ext_vector_type(4)));

__device__ __forceinline__ float fast_exp2(float x) {
#if __has_builtin(__builtin_amdgcn_exp2f)
  return __builtin_amdgcn_exp2f(x);
#else
  return exp2f(x);
#endif
}

// ---------------- fused f32 -> bf16 convert, all 5 tensors in one dispatch ------------
// regions (in 256-f4 blocks): x 16384 | Wq 4096 | Wk 1024 | Wv 1024 | Wo 4096 = 26624
__global__ void cvt_all(const float* __restrict__ x,  const float* __restrict__ Wq,
                        const float* __restrict__ Wk, const float* __restrict__ Wv,
                        const float* __restrict__ Wo, bf16_t* __restrict__ xb,
                        bf16_t* __restrict__ wqkv, bf16_t* __restrict__ wob) {
  const int bid = blockIdx.x, tid = threadIdx.x;
  const float* src; bf16_t* dst; int i;
  if (bid < 16384)      { src = x;  dst = xb;             i = bid * 256 + tid; }
  else if (bid < 20480) { src = Wq; dst = wqkv;           i = (bid - 16384) * 256 + tid; }
  else if (bid < 21504) { src = Wk; dst = wqkv + 4194304; i = (bid - 20480) * 256 + tid; }
  else if (bid < 22528) { src = Wv; dst = wqkv + 5242880; i = (bid - 21504) * 256 + tid; }
  else                  { src = Wo; dst = wob;            i = (bid - 22528) * 256 + tid; }
  float4 v = ((const float4*)src)[i];
  bf16x4 o = { (bf16_t)v.x, (bf16_t)v.y, (bf16_t)v.z, (bf16_t)v.w };
  *(bf16x4*)(dst + (size_t)i * 4) = o;
}

// ---------------- async global->LDS, 16B per lane ----------------
__device__ __forceinline__ void async_load16(const bf16_t* g, bf16_t* l) {
#if __has_builtin(__builtin_amdgcn_global_load_lds)
  __builtin_amdgcn_global_load_lds((const __attribute__((address_space(1))) void*)g,
                                   (__attribute__((address_space(3))) void*)l, 16, 0, 0);
#else
  *(bf16x8*)l = *(const bf16x8*)g;
#endif
}

// ---------------- GEMM: C[M,N] = A[M,K] @ B[N,K]^T ----------------
// 128x128 tile, 4 waves (2x2), BK=64, XOR-chunk-swizzled LDS (0 measured conflicts).
// QKV mode: each bn-block covers exactly one head's 128 dims.
//   bn <  16 : Q head -> RoPE + fold softmax scale*log2e, store bf16 (ldc 2560)
//   16<=bn<20: K head -> RoPE, store bf16 (ldc 2560)
//   bn >= 20 : V head -> store TRANSPOSED into Vt[(b*4+kvh)*128+d][t]
// RoPE pairs (d, d+64) live in partner waves (wc 0/1) -> exchange via the staging LDS
// (free after the K-loop's final barrier).
template<bool F32OUT, bool QKVMODE>
__global__ __launch_bounds__(256) void gemm_bt(const bf16_t* __restrict__ A,
                                               const bf16_t* __restrict__ B,
                                               void* __restrict__ C,
                                               bf16_t* __restrict__ Vt,
                                               const float* __restrict__ F,
                                               int M, int N, int K, int ldc) {
  __shared__ bf16_t smem[2 * 128 * 64];   // Alds | Blds; reused for rope exchange
  bf16_t* Alds = smem;
  bf16_t* Blds = smem + 128 * 64;
  const int tid = threadIdx.x;
  const int wave = tid >> 6, lane = tid & 63;
  const int lrow = lane & 15, quad = lane >> 4;
  const int wr = wave >> 1, wc = wave & 1;
  const int bm = blockIdx.y, bn = blockIdx.x;
  const bf16_t* Ab = A + (size_t)bm * 128 * K;
  const bf16_t* Bb = B + (size_t)bn * 128 * K;
  const int r0 = tid >> 3;
  const int c0 = ((tid & 7) ^ (r0 & 7)) << 3;
  f32x4 acc[4][4] = {};

  for (int kk = 0; kk < K; kk += 64) {
#pragma unroll
    for (int p = 0; p < 4; ++p) {
      async_load16(Ab + (size_t)(p * 32 + r0) * K + kk + c0, &Alds[(p * 256 + tid) * 8]);
      async_load16(Bb + (size_t)(p * 32 + r0) * K + kk + c0, &Blds[(p * 256 + tid) * 8]);
    }
    __syncthreads();
#pragma unroll
    for (int ks2 = 0; ks2 < 2; ++ks2) {
      const int rc = ((ks2 * 4 + quad) ^ (lrow & 7)) << 3;
      bf16x8 af[4], bfv[4];
#pragma unroll
      for (int mt = 0; mt < 4; ++mt)
        af[mt] = *(const bf16x8*)&Alds[(wr * 64 + mt * 16 + lrow) * 64 + rc];
#pragma unroll
      for (int nt = 0; nt < 4; ++nt)
        bfv[nt] = *(const bf16x8*)&Blds[(wc * 64 + nt * 16 + lrow) * 64 + rc];
#pragma unroll
      for (int mt = 0; mt < 4; ++mt)
#pragma unroll
        for (int nt = 0; nt < 4; ++nt)
          acc[mt][nt] = __builtin_amdgcn_mfma_f32_16x16x32_bf16(af[mt], bfv[nt], acc[mt][nt], 0, 0, 0);
    }
    __syncthreads();
  }

  if (QKVMODE) {
    if (bn >= 20) {
      // V head: store transposed. cv = kvh*128+d
#pragma unroll
      for (int mt = 0; mt < 4; ++mt)
#pragma unroll
        for (int nt = 0; nt < 4; ++nt) {
          int row = bm * 128 + wr * 64 + mt * 16 + quad * 4;     // t (4 consecutive)
          int cv  = bn * 128 + wc * 64 + nt * 16 + lrow - 2560;
          int b = row >> 11, tl = row & 2047;
          bf16x4 o;
#pragma unroll
          for (int r = 0; r < 4; ++r) o[r] = (bf16_t)acc[mt][nt][r];
          *(bf16x4*)&Vt[((size_t)(b * 512 + cv)) * 2048 + tl] = o;
        }
      return;
    }
    // Q/K head: RoPE. Stash acc into smem [m*128+n] (bf16), exchange (d, d+64).
#pragma unroll
    for (int mt = 0; mt < 4; ++mt)
#pragma unroll
      for (int nt = 0; nt < 4; ++nt)
#pragma unroll
        for (int r = 0; r < 4; ++r)
          smem[(wr * 64 + mt * 16 + quad * 4 + r) * 128 + (wc * 64 + nt * 16 + lrow)] =
              (bf16_t)acc[mt][nt][r];
    __syncthreads();
    const float2* F2 = (const float2*)F;  // [t][64] (cos,sin)
    const float sc = (bn < 16) ? 0.08838834764831845f * 1.44269504088896340736f : 1.0f;
#pragma unroll
    for (int mt = 0; mt < 4; ++mt)
#pragma unroll
      for (int nt = 0; nt < 4; ++nt) {
        int n = wc * 64 + nt * 16 + lrow;   // d within head (0..127)
#pragma unroll
        for (int r = 0; r < 4; ++r) {
          int m = wr * 64 + mt * 16 + quad * 4 + r;
          int row = bm * 128 + m, t = row & 2047;
          float2 cs = F2[t * 64 + (n & 63)];
          float self = acc[mt][nt][r];
          float part = (float)smem[m * 128 + (n ^ 64)];
          float val = (wc == 0) ? (self * cs.x - part * cs.y)
                                : (self * cs.x + part * cs.y);
          ((bf16_t*)C)[(size_t)row * ldc + bn * 128 + n] = (bf16_t)(val * sc);
        }
      }
    return;
  }

#pragma unroll
  for (int mt = 0; mt < 4; ++mt)
#pragma unroll
    for (int nt = 0; nt < 4; ++nt)
#pragma unroll
      for (int r = 0; r < 4; ++r) {
        int row = bm * 128 + wr * 64 + mt * 16 + quad * 4 + r;
        int col = bn * 128 + wc * 64 + nt * 16 + lrow;
        if (F32OUT) ((float*)C)[(size_t)row * ldc + col] = acc[mt][nt][r];
        else        ((bf16_t*)C)[(size_t)row * ldc + col] = (bf16_t)acc[mt][nt][r];
      }
}

// ---------------- Flash attention, causal, GQA 16q/4kv, D=128 ----------------
// 512 threads (8 waves x 32 q-rows = 256-row Q-tile): K/V staging and barriers amortize
// over 2x the MFMA vs the 4-wave version (K/V L2 traffic halves). Double-buffered K/V via
// global_load_lds w=16 (XOR chunk swizzle); DMA for kt+1 issued right after the single
// barrier, flies during compute of kt. Blocks pair 256-row tiles (qt, 7-qt): uniform 36
// iters. Q arrives pre-roped and pre-scaled (by 1/sqrt(128)*log2e) from the QKV GEMM.
// LDS = 32K(Kdbuf) + 32K(Vdbuf) + 32K(P) = 96 KB -> 1 block/CU, 8 waves.
__global__ __launch_bounds__(512, 2) void attn_kernel(const bf16_t* __restrict__ QKV,
                                                      const bf16_t* __restrict__ Vt,
                                                      bf16_t* __restrict__ O) {
  __shared__ bf16_t Ks[2][64 * 128];   // [buf][key][d], chunk-swizzled
  __shared__ bf16_t Vs[2][128 * 64];   // [buf][d][key], chunk-swizzled
  __shared__ bf16_t Ps[8 * 32 * 64];   // per-wave, chunk-swizzled
  const int tid = threadIdx.x;
  const int wave = tid >> 6, lane = tid & 63;
  const int lrow = lane & 15, quad = lane >> 4;
  const int bh = blockIdx.y, b = bh >> 4, h = bh & 15, kvh = h >> 2;
  const size_t qoff  = ((size_t)b * 2048) * 2560 + (size_t)h * 128;
  const size_t koff  = ((size_t)b * 2048) * 2560 + 2048 + (size_t)kvh * 128;
  const size_t vtoff = ((size_t)(b * 4 + kvh) * 128) * 2048;
  bf16_t* Pw = Ps + wave * (32 * 64);

  // staging indices (512 threads: 2 passes of 512 x 16B per 16KB tile)
  const int krow = tid >> 4;                   // 0..31
  const int kdc  = (tid & 15) ^ (krow & 7);    // K chunk swizzle
  const int vrow = tid >> 3;                   // 0..63
  const int vkc  = (tid & 7) ^ (vrow & 7);     // V chunk swizzle

  auto stage = [&](int kt, int bsel) {
    const bf16_t* Kg = QKV + koff + (size_t)(kt * 64) * 2560;
    const bf16_t* Vg = Vt + vtoff + kt * 64;
    bf16_t* Kd = &Ks[bsel][0];
    bf16_t* Vd = &Vs[bsel][0];
#pragma unroll
    for (int p = 0; p < 2; ++p) {
      int ci = p * 512 + tid;
      async_load16(Kg + (size_t)(p * 32 + krow) * 2560 + kdc * 8, Kd + ci * 8);
      async_load16(Vg + (size_t)(p * 64 + vrow) * 2048 + vkc * 8, Vd + ci * 8);
    }
  };

  for (int phase = 0; phase < 2; ++phase) {
    const int qt = phase ? (7 - blockIdx.x) : blockIdx.x;   // 256-row tile index
    const int qbase = qt * 256 + wave * 32;

    // Q B-frags (pre-roped, pre-scaled): B[n=q][k=d]
    bf16x8 qf[2][4];
#pragma unroll
    for (int nt2 = 0; nt2 < 2; ++nt2) {
      const bf16_t* qp = QKV + qoff + (size_t)(qbase + nt2 * 16 + lrow) * 2560 + quad * 8;
#pragma unroll
      for (int ks = 0; ks < 4; ++ks) qf[nt2][ks] = *(const bf16x8*)(qp + ks * 32);
    }

    f32x4 Oacc[2][8] = {};
    float m_r[2] = {-1.0e30f, -1.0e30f};
    float l_r[2] = {0.f, 0.f};
    const int kt_end = 4 * qt + 4;

    stage(0, 0);  // prime; kt_end is even so last iter uses buf 1 -> no phase hazard

    for (int kt = 0; kt < kt_end; ++kt) {
      // Single barrier: drains tile-kt DMA and protects the buffer kt+1 overwrites.
      __syncthreads();
      if (kt + 1 < kt_end) stage(kt + 1, (kt + 1) & 1);
      const bf16_t* Kb_ = &Ks[kt & 1][0];
      const bf16_t* Vb_ = &Vs[kt & 1][0];

      if (kt * 64 <= qbase + 31) {  // wave-uniform skip of fully-masked tiles
        // S^T = K Q^T : C[m=key][n=q]
        f32x4 S[2][4] = {};
#pragma unroll
        for (int ks = 0; ks < 4; ++ks) {
          bf16x8 kf[4];
#pragma unroll
          for (int mt = 0; mt < 4; ++mt) {
            int dc = (ks * 4 + quad) ^ (lrow & 7);
            kf[mt] = *(const bf16x8*)&Kb_[(mt * 16 + lrow) * 128 + dc * 8];
          }
#pragma unroll
          for (int nt2 = 0; nt2 < 2; ++nt2)
#pragma unroll
            for (int mt = 0; mt < 4; ++mt)
              S[nt2][mt] = __builtin_amdgcn_mfma_f32_16x16x32_bf16(kf[mt], qf[nt2][ks], S[nt2][mt], 0, 0, 0);
        }
        // causal mask (diagonal tiles only). S^T: key=row, q=col.
        if (kt * 64 + 63 > qbase) {
#pragma unroll
          for (int nt2 = 0; nt2 < 2; ++nt2) {
            int q = qbase + nt2 * 16 + lrow;
#pragma unroll
            for (int mt = 0; mt < 4; ++mt) {
              int key0 = kt * 64 + mt * 16 + quad * 4;
#pragma unroll
              for (int r = 0; r < 4; ++r)
                if (key0 + r > q) S[nt2][mt][r] = -1.0e30f;
            }
          }
        }
        // online softmax (log2 domain); P -> Pw with chunk swizzle
        float alpha[2];
#pragma unroll
        for (int nt2 = 0; nt2 < 2; ++nt2) {
          float mx = -1.0e30f;
#pragma unroll
          for (int mt = 0; mt < 4; ++mt)
#pragma unroll
            for (int r = 0; r < 4; ++r) mx = fmaxf(mx, S[nt2][mt][r]);
          mx = fmaxf(mx, __shfl_xor(mx, 16, 64));
          mx = fmaxf(mx, __shfl_xor(mx, 32, 64));
          float mnew = fmaxf(m_r[nt2], mx);
          alpha[nt2] = fast_exp2(m_r[nt2] - mnew);
          m_r[nt2] = mnew;
          float rs = 0.f;
          const int prow = nt2 * 16 + lrow;
          const int pbase = prow * 64 + ((quad & 1) << 2);
#pragma unroll
          for (int mt = 0; mt < 4; ++mt) {
            bf16x4 pk;
#pragma unroll
            for (int r = 0; r < 4; ++r) {
              float p = fast_exp2(S[nt2][mt][r] - mnew);
              rs += p;
              pk[r] = (bf16_t)p;
            }
            int c8 = ((mt * 2 + (quad >> 1)) ^ (prow & 7)) << 3;
            *(bf16x4*)&Pw[pbase + c8] = pk;
          }
          rs += __shfl_xor(rs, 16, 64);
          rs += __shfl_xor(rs, 32, 64);
          l_r[nt2] = l_r[nt2] * alpha[nt2] + rs;
        }
        // lazy O rescale
        bool nz = (alpha[0] != 1.f) || (alpha[1] != 1.f);
        if (__ballot(nz) != 0ull) {
#pragma unroll
          for (int mt2 = 0; mt2 < 2; ++mt2)
#pragma unroll
            for (int r = 0; r < 4; ++r) {
              float av = __shfl(alpha[mt2], quad * 4 + r, 16);
#pragma unroll
              for (int dt = 0; dt < 8; ++dt) Oacc[mt2][dt][r] *= av;
            }
        }
        // O += P V : A=P from Pw (swizzled), B=V^T from Vs (swizzled)
#pragma unroll
        for (int ks2 = 0; ks2 < 2; ++ks2) {
          bf16x8 ap[2];
#pragma unroll
          for (int mt2 = 0; mt2 < 2; ++mt2) {
            int prow = mt2 * 16 + lrow;
            ap[mt2] = *(const bf16x8*)&Pw[prow * 64 + (((ks2 * 4 + quad) ^ (prow & 7)) << 3)];
          }
          int dc = (ks2 * 4 + quad) ^ (lrow & 7);
#pragma unroll
          for (int dt = 0; dt < 8; ++dt) {
            bf16x8 bv = *(const bf16x8*)&Vb_[(dt * 16 + lrow) * 64 + dc * 8];
#pragma unroll
            for (int mt2 = 0; mt2 < 2; ++mt2)
              Oacc[mt2][dt] = __builtin_amdgcn_mfma_f32_16x16x32_bf16(ap[mt2], bv, Oacc[mt2][dt], 0, 0, 0);
          }
        }
      }
    }

    // epilogue: O /= l, store bf16 (stride 2048)
#pragma unroll
    for (int mt2 = 0; mt2 < 2; ++mt2)
#pragma unroll
      for (int r = 0; r < 4; ++r) {
        float lv = __shfl(l_r[mt2], quad * 4 + r, 16);
        float inv = 1.0f / lv;
        int row = qbase + mt2 * 16 + quad * 4 + r;
#pragma unroll
        for (int dt = 0; dt < 8; ++dt)
          O[(size_t)b * 2048 * 2048 + (size_t)row * 2048 + h * 128 + dt * 16 + lrow] =
              (bf16_t)(Oacc[mt2][dt][r] * inv);
      }
  }
}

// ---------------- launch ----------------
extern "C" void kernel_launch(void* const* d_in, const int* in_sizes, int n_in,
                              void* d_out, int out_size, void* d_ws, size_t ws_size,
                              hipStream_t stream) {
  const float* x  = (const float*)d_in[0];
  const float* fc = (const float*)d_in[1];
  const float* Wq = (const float*)d_in[2];
  const float* Wk = (const float*)d_in[3];
  const float* Wv = (const float*)d_in[4];
  const float* Wo = (const float*)d_in[5];
  float* out = (float*)d_out;

  char* ws = (char*)d_ws;
  size_t off = 0;
  auto alloc = [&](size_t bytes) { char* p = ws + off; off += bytes; return p; };
  bf16_t* xb    = (bf16_t*)alloc((size_t)8192 * 2048 * 2);  // x bf16
  bf16_t* Wqkvb = (bf16_t*)alloc((size_t)3072 * 2048 * 2);  // [Wq; Wk; Wv] rows
  bf16_t* Wob   = (bf16_t*)alloc((size_t)2048 * 2048 * 2);
  bf16_t* QKVb  = (bf16_t*)alloc((size_t)8192 * 2560 * 2);  // [t][ Q(2048, roped+scaled) | K(512, roped) ]
  bf16_t* Ab    = (bf16_t*)alloc((size_t)8192 * 2048 * 2);
  bf16_t* Vtb   = (bf16_t*)alloc((size_t)2048 * 2048 * 2);  // V^T [(b*4+kvh)*128+d][t]
  (void)ws_size; (void)in_sizes; (void)n_in; (void)out_size;

  cvt_all<<<26624, 256, 0, stream>>>(x, Wq, Wk, Wv, Wo, xb, Wqkvb, Wob);

  // fused QKV projection + RoPE(Q,K) + softmax-scale fold + V transpose
  gemm_bt<false, true><<<dim3(24, 64), 256, 0, stream>>>(xb, Wqkvb, QKVb, Vtb, fc,
                                                         8192, 3072, 2048, 2560);

  attn_kernel<<<dim3(4, 64), 512, 0, stream>>>(QKVb, Vtb, Ab);

  gemm_bt<true, false><<<dim3(16, 64), 256, 0, stream>>>(Ab, Wob, out, nullptr, nullptr,
                                                         8192, 2048, 2048, 2048);
}